// Round 10
// baseline (1585.189 us; speedup 1.0000x reference)
//
#include <hip/hip_runtime.h>

#define HS    128
#define INP   23
#define NGATE 512
#define TLEN  1024
#define BATCH 512

typedef short  bf8   __attribute__((ext_vector_type(8)));   // 8 bf16 (4 VGPR)
typedef float  f32x4 __attribute__((ext_vector_type(4)));

__device__ __forceinline__ float fexp(float x) {
    return __builtin_amdgcn_exp2f(x * 1.4426950408889634f);
}
__device__ __forceinline__ float fsigmoid(float x) {
    return __builtin_amdgcn_rcpf(1.0f + fexp(-x));
}
__device__ __forceinline__ float ftanh(float x) {
    return 2.0f * fsigmoid(2.0f * x) - 1.0f;
}
__device__ __forceinline__ short bf16r(float x) {   // round-to-nearest-even
    unsigned u = __float_as_uint(x);
    u += 0x7fffu + ((u >> 16) & 1u);
    return (short)(u >> 16);
}

// ---------------------------------------------------------------------------
// Repack U' = [U(128) ; W(24) ; bias(1) ; 0(7)]  (K=160, 5 ksteps of 32)
// into bf16 B-fragment order:
//   Upk[cb<32][s<5][lane<64][e<8] = U'[s*32 + 8*(lane>>4)+e][cb*16+(lane&15)]
// Bias folded at k=152 (pairs with constant 1.0 in the A-fragment).
// 160 KB into d_ws; rewritten every launch (ws is re-poisoned).
// ---------------------------------------------------------------------------
__global__ void repack_kernel(const float* __restrict__ W,
                              const float* __restrict__ U,
                              const float* __restrict__ bias,
                              short* __restrict__ ws)
{
    const int id = blockIdx.x * 256 + threadIdx.x;   // 40*256 = 10240
    if (id >= 10240) return;
    const int l   = id & 63;
    const int s   = (id >> 6) % 5;
    const int cb  = (id >> 6) / 5;
    const int col = cb * 16 + (l & 15);
    const int kb  = s * 32 + ((l >> 4) << 3);
    short tmp[8];
    #pragma unroll
    for (int e = 0; e < 8; ++e) {
        const int k = kb + e;
        float v;
        if      (k < 128) v = U[k * NGATE + col];
        else if (k < 152) v = W[(k - 128) * NGATE + col];
        else if (k == 152) v = bias[col];
        else               v = 0.0f;
        tmp[e] = bf16r(v);
    }
    *(bf8*)(ws + id * 8) = *(const bf8*)tmp;
}

// ---------------------------------------------------------------------------
// Main: 512 WGs x 512 thr (8 waves) = 2 WGs/CU (cross-WG latency hiding).
// M=1 batch row per WG. Wave w owns h-cols [16w,16w+16) and computes
// col-blocks {w, 8+w, 16+w, 24+w} = i,f,g,o for its own cols -> after the
// 20 MFMAs, lane l<16 holds ALL FOUR gates of cell j=16w+l in registers.
// No gate exchange, ONE barrier per step. x + bias folded into the K=160
// recurrence (5th kstep of the A-frag carries [x(t) | 1.0 | 0...]).
// B-frags: 20 x bf8 = 80 VGPR, volatile-asm loaded once (pinned; total
// demand ~121 < the 128 budget this toolchain grants -> no spill).
// ---------------------------------------------------------------------------
#define MFMA __builtin_amdgcn_mfma_f32_16x16x32_bf16

__global__
__attribute__((amdgpu_flat_work_group_size(512, 512)))
void lstm_mfma3(const float* __restrict__ points,
                const float* __restrict__ times,
                const float* __restrict__ Wc,
                const float* __restrict__ bc,
                float* __restrict__ out,
                const short* __restrict__ ws)
{
    const int b   = blockIdx.x;       // batch row (M=1)
    const int tid = threadIdx.x;
    const int w   = tid >> 6;         // wave 0..7
    const int l   = tid & 63;

    __shared__ __align__(16) short hfrag[2][5][64][8];  // 10 KB, A-frag layout
    __shared__ float opart[2][8][2];                    // per-wave outproj partials

    // ---- B-fragments: 20 x 16B volatile-asm loads (register-pinned) ----
    bf8 B00,B01,B02,B03,B04, B10,B11,B12,B13,B14,
        B20,B21,B22,B23,B24, B30,B31,B32,B33,B34;
#define LDB(dst, gi, s_) { const short* p_ = ws + (((((gi)*8 + w)*5 + (s_))*64 + l) * 8); \
    asm volatile("global_load_dwordx4 %0, %1, off" : "=v"(dst) : "v"(p_)); }
    LDB(B00,0,0) LDB(B01,0,1) LDB(B02,0,2) LDB(B03,0,3) LDB(B04,0,4)
    LDB(B10,1,0) LDB(B11,1,1) LDB(B12,1,2) LDB(B13,1,3) LDB(B14,1,4)
    LDB(B20,2,0) LDB(B21,2,1) LDB(B22,2,2) LDB(B23,2,3) LDB(B24,2,4)
    LDB(B30,3,0) LDB(B31,3,1) LDB(B32,3,2) LDB(B33,3,3) LDB(B34,3,4)
#undef LDB
    asm volatile("s_waitcnt vmcnt(0)" ::: "memory");
    __builtin_amdgcn_sched_barrier(0);

    const int j = (w << 4) | (l & 15);            // this lane's h column
    const float wc0 = Wc[2 * j], wc1 = Wc[2 * j + 1];
    const float bc0 = bc[0], bc1 = bc[1];
    float c = 0.0f;

    // ---- init LDS: zero both hfrag buffers, then constants + x(0) ----
    {
        int* hp = (int*)&hfrag[0][0][0][0];       // 2560 ints / 512 thr
        #pragma unroll
        for (int i = 0; i < 5; ++i) hp[tid + i * 512] = 0;
    }
    __syncthreads();
    if (tid == 0) {       // A[row0][k=152] = 1.0 (pairs with bias row of U')
        hfrag[0][4][48][0] = (short)0x3F80;
        hfrag[1][4][48][0] = (short)0x3F80;
    }
    float xhold = 0.0f;   // x prefetch register (wave 1, lanes 16..39)
    if (w == 1 && l >= 16 && l < 40) {
        const int f = l - 16;                     // feature 0..23
        const float v0 = (f < INP) ? points[(size_t)b * TLEN * INP + f]
                                   : times[(size_t)b * TLEN];
        hfrag[0][4][(f >> 3) << 4][f & 7] = bf16r(v0);
        xhold = (f < INP) ? points[((size_t)b * TLEN + 1) * INP + f]
                          : times[(size_t)b * TLEN + 1];
    }
    __syncthreads();

    for (int t = 0; t < TLEN; ++t) {
        const int cur = t & 1, nxt = cur ^ 1;

        // x: stage x(t+1) from xhold; issue load of x(t+2) (1-step latency)
        if (w == 1 && l >= 16 && l < 40) {
            const int f = l - 16;
            hfrag[nxt][4][(f >> 3) << 4][f & 7] = bf16r(xhold);
            const int tt = (t + 2 < TLEN) ? t + 2 : TLEN - 1;
            xhold = (f < INP) ? points[((size_t)b * TLEN + tt) * INP + f]
                              : times[(size_t)b * TLEN + tt];
        }

        // ---- 20 MFMAs: 5 ksteps x {i,f,g,o}; acc starts 0 (bias in k=152) ----
        f32x4 a0 = {0,0,0,0}, a1 = {0,0,0,0}, a2 = {0,0,0,0}, a3 = {0,0,0,0};
#define KSTEP(s_, Ba, Bb, Bc2, Bd) { \
        const bf8 ha = *(const bf8*)&hfrag[cur][s_][l][0]; \
        a0 = MFMA(ha, Ba,  a0, 0, 0, 0); \
        a1 = MFMA(ha, Bb,  a1, 0, 0, 0); \
        a2 = MFMA(ha, Bc2, a2, 0, 0, 0); \
        a3 = MFMA(ha, Bd,  a3, 0, 0, 0); }
        KSTEP(0, B00, B10, B20, B30)
        KSTEP(1, B01, B11, B21, B31)
        KSTEP(2, B02, B12, B22, B32)
        KSTEP(3, B03, B13, B23, B33)
        KSTEP(4, B04, B14, B24, B34)
#undef KSTEP

        // ---- in-lane cell update (lanes 0-15 of every wave) ----
        if (l < 16) {
            const float ig = fsigmoid(a0[0]);
            const float fg = fsigmoid(a1[0]);
            const float gg = ftanh(a2[0]);
            const float og = fsigmoid(a3[0]);
            c = fg * c + ig * gg;
            const float h = og * ftanh(c);
            // h -> A-frag slot: kstep j>>5, lane 16*((j>>3)&3), elem j&7
            hfrag[nxt][j >> 5][((j >> 3) & 3) << 4][j & 7] = bf16r(h);

            // outproj partial over this wave's 16 cols (4-deep shfl)
            float p0 = h * wc0, p1 = h * wc1;
            p0 += __shfl_xor(p0, 1);  p1 += __shfl_xor(p1, 1);
            p0 += __shfl_xor(p0, 2);  p1 += __shfl_xor(p1, 2);
            p0 += __shfl_xor(p0, 4);  p1 += __shfl_xor(p1, 4);
            p0 += __shfl_xor(p0, 8);  p1 += __shfl_xor(p1, 8);
            if (l == 0) { opart[cur][w][0] = p0; opart[cur][w][1] = p1; }
        }

        // ---- deferred finish of out(t-1) (wave 2, lanes 16-17; off-path) ----
        if (t > 0 && w == 2 && (l == 16 || l == 17)) {
            const int o = l - 16;
            float v = o ? bc1 : bc0;
            #pragma unroll
            for (int wv = 0; wv < 8; ++wv) v += opart[nxt][wv][o];
            out[((size_t)b * TLEN + (t - 1)) * 2 + o] = fsigmoid(v);
        }

        __syncthreads();   // the single per-step barrier
    }

    // epilogue: out(TLEN-1), opart[(TLEN-1)&1] = opart[1]
    if (w == 2 && (l == 16 || l == 17)) {
        const int o = l - 16;
        float v = o ? bc1 : bc0;
        #pragma unroll
        for (int wv = 0; wv < 8; ++wv) v += opart[1][wv][o];
        out[((size_t)b * TLEN + (TLEN - 1)) * 2 + o] = fsigmoid(v);
    }
}

extern "C" void kernel_launch(void* const* d_in, const int* in_sizes, int n_in,
                              void* d_out, int out_size, void* d_ws, size_t ws_size,
                              hipStream_t stream) {
    const float* points = (const float*)d_in[0];
    const float* times  = (const float*)d_in[1];
    const float* W      = (const float*)d_in[2];
    const float* U      = (const float*)d_in[3];
    const float* bias   = (const float*)d_in[4];
    const float* Wc     = (const float*)d_in[5];
    const float* bc     = (const float*)d_in[6];
    float* out = (float*)d_out;
    short* ws  = (short*)d_ws;          // 160 KB (U'pk, K=160 x 512 cols bf16)

    repack_kernel<<<dim3(40), dim3(256), 0, stream>>>(W, U, bias, ws);
    lstm_mfma3<<<dim3(BATCH), dim3(512), 0, stream>>>(
        points, times, Wc, bc, out, ws);
}

// Round 11
// 1148.631 us; speedup vs baseline: 1.3801x; 1.3801x over previous
//
#include <hip/hip_runtime.h>

#define HS    128
#define INP   23
#define NGATE 512
#define TLEN  1024
#define BATCH 512

typedef short  bf8   __attribute__((ext_vector_type(8)));   // 8 bf16 (4 VGPR)
typedef float  f32x4 __attribute__((ext_vector_type(4)));

__device__ __forceinline__ float fexp(float x) {
    return __builtin_amdgcn_exp2f(x * 1.4426950408889634f);
}
__device__ __forceinline__ float fsigmoid(float x) {
    return __builtin_amdgcn_rcpf(1.0f + fexp(-x));
}
__device__ __forceinline__ float ftanh(float x) {
    return 2.0f * fsigmoid(2.0f * x) - 1.0f;
}
__device__ __forceinline__ short bf16r(float x) {   // round-to-nearest-even
    unsigned u = __float_as_uint(x);
    u += 0x7fffu + ((u >> 16) & 1u);
    return (short)(u >> 16);
}

// ---------------------------------------------------------------------------
// Repack U' = [U(128) ; W(24) ; bias(1) ; 0(7)]  (K=160, 5 ksteps) into bf16
// B-frag order: Upk[cb][s][lane][e] = U'[s*32+8*(lane>>4)+e][cb*16+(lane&15)].
// Verbatim r10 (correctness-verified, absmax 0.0039). 160 KB into d_ws.
// ---------------------------------------------------------------------------
__global__ void repack_kernel(const float* __restrict__ W,
                              const float* __restrict__ U,
                              const float* __restrict__ bias,
                              short* __restrict__ ws)
{
    const int id = blockIdx.x * 256 + threadIdx.x;   // 40*256 = 10240
    if (id >= 10240) return;
    const int l   = id & 63;
    const int s   = (id >> 6) % 5;
    const int cb  = (id >> 6) / 5;
    const int col = cb * 16 + (l & 15);
    const int kb  = s * 32 + ((l >> 4) << 3);
    short tmp[8];
    #pragma unroll
    for (int e = 0; e < 8; ++e) {
        const int k = kb + e;
        float v;
        if      (k < 128)  v = U[k * NGATE + col];
        else if (k < 152)  v = W[(k - 128) * NGATE + col];
        else if (k == 152) v = bias[col];
        else               v = 0.0f;
        tmp[e] = bf16r(v);
    }
    *(bf8*)(ws + id * 8) = *(const bf8*)tmp;
}

#define MFMA __builtin_amdgcn_mfma_f32_16x16x32_bf16

// Raw barrier WITHOUT vmcnt drain (m201 pattern): LDS ordering via lgkmcnt(0);
// sched_barrier(0) fences compiler motion; global loads/stores stay in flight.
__device__ __forceinline__ void step_barrier() {
    asm volatile("s_waitcnt lgkmcnt(0)" ::: "memory");
    __builtin_amdgcn_sched_barrier(0);
    __builtin_amdgcn_s_barrier();
    __builtin_amdgcn_sched_barrier(0);
}

// ---------------------------------------------------------------------------
// Main: 256 WGs x 512 thr (8 waves) = 1 WG/CU, whole batch in ONE pass
// (r10 ran 512 WGs at 1 WG/CU -> two passes; that was half the loss).
// M=2: A-frag rows 0,1 = batch rows b0,b0+1. Wave w owns h-cols [16w,16w+16)
// and computes col-blocks {w,8+w,16+w,24+w} = i,f,g,o in-lane (r10-verified).
// One raw barrier/step; x-loads + out-stores fly across it (no vmcnt drain —
// r10's other loss: __syncthreads drained the streaming x-load every step).
// ---------------------------------------------------------------------------
__global__
__attribute__((amdgpu_flat_work_group_size(512, 512)))
void lstm_mfma4(const float* __restrict__ points,
                const float* __restrict__ times,
                const float* __restrict__ Wc,
                const float* __restrict__ bc,
                float* __restrict__ out,
                const short* __restrict__ ws)
{
    const int b0  = blockIdx.x * 2;
    const int tid = threadIdx.x;
    const int w   = tid >> 6;          // wave 0..7
    const int l   = tid & 63;

    __shared__ __align__(16) short hfrag[2][5][64][8];  // 10 KB, A-frag layout
    __shared__ float opart[2][8][2][2];                 // [par][wave][row][col]

    // ---- B-fragments: 20 x 16B volatile-asm loads (pinned, loaded once) ----
    bf8 B00,B01,B02,B03,B04, B10,B11,B12,B13,B14,
        B20,B21,B22,B23,B24, B30,B31,B32,B33,B34;
#define LDB(dst, gi, s_) { const short* p_ = ws + (((((gi)*8 + w)*5 + (s_))*64 + l) * 8); \
    asm volatile("global_load_dwordx4 %0, %1, off" : "=v"(dst) : "v"(p_)); }
    LDB(B00,0,0) LDB(B01,0,1) LDB(B02,0,2) LDB(B03,0,3) LDB(B04,0,4)
    LDB(B10,1,0) LDB(B11,1,1) LDB(B12,1,2) LDB(B13,1,3) LDB(B14,1,4)
    LDB(B20,2,0) LDB(B21,2,1) LDB(B22,2,2) LDB(B23,2,3) LDB(B24,2,4)
    LDB(B30,3,0) LDB(B31,3,1) LDB(B32,3,2) LDB(B33,3,3) LDB(B34,3,4)
#undef LDB
    asm volatile("s_waitcnt vmcnt(0)" ::: "memory");
    __builtin_amdgcn_sched_barrier(0);

    const int j    = (w << 4) | (l & 15);      // this lane's h column
    const int hgrp = ((j >> 3) & 3) << 4;      // h-write lane-group
    const int hks  = j >> 5;                   // h-write kstep
    const float wc0 = Wc[2 * j], wc1 = Wc[2 * j + 1];
    const float bc0 = bc[0], bc1 = bc[1];
    float c0 = 0.f, c1 = 0.f, hp0 = 0.f, hp1 = 0.f;

    // x-lanes: wave 1, lanes 16..63 -> (row, feature)
    const bool xlane = (w == 1 && l >= 16);
    int xr = 0, xf = 0; const float* xsrc = nullptr; size_t xstep = 0;
    if (xlane) {
        const int xi = l - 16;
        xr = (xi >= 24); xf = xi - 24 * xr;
        if (xf < INP) { xsrc = points + (size_t)(b0 + xr) * TLEN * INP + xf; xstep = INP; }
        else          { xsrc = times  + (size_t)(b0 + xr) * TLEN;           xstep = 1;   }
    }
    // out-lanes: wave 2, lanes 16..19 -> (row, outcol)
    const bool olane = (w == 2 && l >= 16 && l < 20);
    const int orr = (l >> 1) & 1, oo = l & 1;

    // ---- init LDS: zero both hfrag buffers; const 1.0 at k=152; x(0) ----
    {
        int* hz = (int*)&hfrag[0][0][0][0];    // 2560 ints
        #pragma unroll
        for (int i = 0; i < 5; ++i) hz[tid + 512 * i] = 0;
    }
    __syncthreads();
    if (tid < 2) {                             // A[row tid][k=152] = 1.0 (bias row)
        hfrag[0][4][48 + tid][0] = (short)0x3F80;
        hfrag[1][4][48 + tid][0] = (short)0x3F80;
    }
    float xhA = 0.f, xhB = 0.f;
    if (xlane) {
        hfrag[0][4][xr + ((xf >> 3) << 4)][xf & 7] = bf16r(xsrc[0]);   // x(0)
        xhA = xsrc[xstep];          // x(1) -> staged at iter 0
        xhB = xsrc[2 * xstep];      // x(2) -> staged at iter 1
    }
    __syncthreads();

#define STEP(t, CUR, NXT, XH) do {                                              \
    /* MFMA: 5 ksteps x {i,f,g,o} (in-lane gates, r10-verified mapping) */      \
    f32x4 a0 = {0.f,0.f,0.f,0.f}, a1 = a0, a2 = a0, a3 = a0;                    \
    { const bf8 ha = *(const bf8*)&hfrag[CUR][0][l][0];                         \
      a0=MFMA(ha,B00,a0,0,0,0); a1=MFMA(ha,B10,a1,0,0,0);                       \
      a2=MFMA(ha,B20,a2,0,0,0); a3=MFMA(ha,B30,a3,0,0,0); }                     \
    { const bf8 ha = *(const bf8*)&hfrag[CUR][1][l][0];                         \
      a0=MFMA(ha,B01,a0,0,0,0); a1=MFMA(ha,B11,a1,0,0,0);                       \
      a2=MFMA(ha,B21,a2,0,0,0); a3=MFMA(ha,B31,a3,0,0,0); }                     \
    { const bf8 ha = *(const bf8*)&hfrag[CUR][2][l][0];                         \
      a0=MFMA(ha,B02,a0,0,0,0); a1=MFMA(ha,B12,a1,0,0,0);                       \
      a2=MFMA(ha,B22,a2,0,0,0); a3=MFMA(ha,B32,a3,0,0,0); }                     \
    { const bf8 ha = *(const bf8*)&hfrag[CUR][3][l][0];                         \
      a0=MFMA(ha,B03,a0,0,0,0); a1=MFMA(ha,B13,a1,0,0,0);                       \
      a2=MFMA(ha,B23,a2,0,0,0); a3=MFMA(ha,B33,a3,0,0,0); }                     \
    { const bf8 ha = *(const bf8*)&hfrag[CUR][4][l][0];                         \
      a0=MFMA(ha,B04,a0,0,0,0); a1=MFMA(ha,B14,a1,0,0,0);                       \
      a2=MFMA(ha,B24,a2,0,0,0); a3=MFMA(ha,B34,a3,0,0,0); }                     \
    /* out-projection partials of h(t-1) (VALU, overlaps the MFMA pipe) */      \
    if (l < 16) {                                                               \
        float p00 = hp0*wc0, p01 = hp0*wc1, p10 = hp1*wc0, p11 = hp1*wc1;       \
        p00 += __shfl_xor(p00,1); p01 += __shfl_xor(p01,1);                     \
        p10 += __shfl_xor(p10,1); p11 += __shfl_xor(p11,1);                     \
        p00 += __shfl_xor(p00,2); p01 += __shfl_xor(p01,2);                     \
        p10 += __shfl_xor(p10,2); p11 += __shfl_xor(p11,2);                     \
        p00 += __shfl_xor(p00,4); p01 += __shfl_xor(p01,4);                     \
        p10 += __shfl_xor(p10,4); p11 += __shfl_xor(p11,4);                     \
        p00 += __shfl_xor(p00,8); p01 += __shfl_xor(p01,8);                     \
        p10 += __shfl_xor(p10,8); p11 += __shfl_xor(p11,8);                     \
        if (l == 0) { opart[CUR][w][0][0] = p00; opart[CUR][w][0][1] = p01;     \
                      opart[CUR][w][1][0] = p10; opart[CUR][w][1][1] = p11; } } \
    /* stage x(t+1); issue load of x(t+3) (flies across 2 raw barriers) */      \
    if (xlane) {                                                                \
        hfrag[NXT][4][xr + ((xf >> 3) << 4)][xf & 7] = bf16r(XH);               \
        const size_t tt = ((t) + 3 < TLEN) ? (size_t)((t) + 3) : (TLEN - 1);    \
        XH = xsrc[tt * xstep]; }                                                \
    /* finish + store out(t-2) (store flies, never waited on) */                \
    if ((t) >= 2 && olane) {                                                    \
        float v = oo ? bc1 : bc0;                                               \
        for (int wv = 0; wv < 8; ++wv) v += opart[NXT][wv][orr][oo];            \
        out[((size_t)(b0 + orr) * TLEN + ((t) - 2)) * 2 + oo] = fsigmoid(v); }  \
    /* cell update for both batch rows (acc rows 0,1) + h publish */            \
    if (l < 16) {                                                               \
        const float i0=fsigmoid(a0[0]), f0=fsigmoid(a1[0]);                     \
        const float g0=ftanh(a2[0]),   o0=fsigmoid(a3[0]);                      \
        c0 = f0*c0 + i0*g0;  const float h0 = o0*ftanh(c0);                     \
        const float i1=fsigmoid(a0[1]), f1=fsigmoid(a1[1]);                     \
        const float g1=ftanh(a2[1]),   o1=fsigmoid(a3[1]);                      \
        c1 = f1*c1 + i1*g1;  const float h1 = o1*ftanh(c1);                     \
        hfrag[NXT][hks][0 | hgrp][j & 7] = bf16r(h0);                           \
        hfrag[NXT][hks][1 | hgrp][j & 7] = bf16r(h1);                           \
        hp0 = h0; hp1 = h1; }                                                   \
    step_barrier();                                                             \
} while (0)

    for (int t = 0; t < TLEN; t += 2) {
        STEP(t,     0, 1, xhA);
        STEP(t + 1, 1, 0, xhB);
    }
#undef STEP

    // ---- epilogue: out(1022) from opart[1]; reduce h(1023) -> out(1023) ----
    if (l < 16) {
        float p00 = hp0*wc0, p01 = hp0*wc1, p10 = hp1*wc0, p11 = hp1*wc1;
        p00 += __shfl_xor(p00,1); p01 += __shfl_xor(p01,1);
        p10 += __shfl_xor(p10,1); p11 += __shfl_xor(p11,1);
        p00 += __shfl_xor(p00,2); p01 += __shfl_xor(p01,2);
        p10 += __shfl_xor(p10,2); p11 += __shfl_xor(p11,2);
        p00 += __shfl_xor(p00,4); p01 += __shfl_xor(p01,4);
        p10 += __shfl_xor(p10,4); p11 += __shfl_xor(p11,4);
        p00 += __shfl_xor(p00,8); p01 += __shfl_xor(p01,8);
        p10 += __shfl_xor(p10,8); p11 += __shfl_xor(p11,8);
        if (l == 0) { opart[0][w][0][0] = p00; opart[0][w][0][1] = p01;
                      opart[0][w][1][0] = p10; opart[0][w][1][1] = p11; }
    }
    if (olane) {   // out(1022): opart[1] written at iter t=1023 (barrier'd)
        float v = oo ? bc1 : bc0;
        for (int wv = 0; wv < 8; ++wv) v += opart[1][wv][orr][oo];
        out[((size_t)(b0 + orr) * TLEN + 1022) * 2 + oo] = fsigmoid(v);
    }
    __syncthreads();
    if (olane) {   // out(1023)
        float v = oo ? bc1 : bc0;
        for (int wv = 0; wv < 8; ++wv) v += opart[0][wv][orr][oo];
        out[((size_t)(b0 + orr) * TLEN + 1023) * 2 + oo] = fsigmoid(v);
    }
}

extern "C" void kernel_launch(void* const* d_in, const int* in_sizes, int n_in,
                              void* d_out, int out_size, void* d_ws, size_t ws_size,
                              hipStream_t stream) {
    const float* points = (const float*)d_in[0];
    const float* times  = (const float*)d_in[1];
    const float* W      = (const float*)d_in[2];
    const float* U      = (const float*)d_in[3];
    const float* bias   = (const float*)d_in[4];
    const float* Wc     = (const float*)d_in[5];
    const float* bc     = (const float*)d_in[6];
    float* out = (float*)d_out;
    short* ws  = (short*)d_ws;          // 160 KB (U'pk, K=160 x 512 cols bf16)

    repack_kernel<<<dim3(40), dim3(256), 0, stream>>>(W, U, bias, ws);
    lstm_mfma4<<<dim3(BATCH / 2), dim3(512), 0, stream>>>(
        points, times, Wc, bc, out, ws);
}